// Round 2
// 1807.060 us; speedup vs baseline: 1.0877x; 1.0877x over previous
//
#include <hip/hip_runtime.h>
#include <stdint.h>
#include <stddef.h>

// ---------------------------------------------------------------------------
// FedLite quantize: 8 independent KMeans (N=4096, d=1024, L=64, 10 iters)
// pts = x viewed as [R=8][N=4096][SUBD=1024] (reshape is layout-preserving).
// Init indices reproduce jax.random (threefry2x32, partitionable mode).
// ---------------------------------------------------------------------------

#define JAX_PARTITIONABLE 1

static constexpr int R_    = 8;
static constexpr int N_    = 4096;
static constexpr int L_    = 64;
static constexpr int D_    = 1024;   // SUBD
static constexpr int ITERS = 10;
static constexpr int ROWS  = R_ * N_;   // 32768 total sub-vectors
static constexpr int SEGS  = 8;         // n-segments for deterministic partial sums

// ---------------------------------------------------------------------------
// Threefry2x32 (JAX flavor): 20 rounds, rotations {13,15,26,6}/{17,29,16,24}
// ---------------------------------------------------------------------------
__device__ __forceinline__ unsigned rotl32(unsigned x, int r) {
  return (x << r) | (x >> (32 - r));
}

__device__ __forceinline__ void tf2x32(unsigned k0, unsigned k1,
                                       unsigned c0, unsigned c1,
                                       unsigned &o0, unsigned &o1) {
  unsigned ks2 = k0 ^ k1 ^ 0x1BD11BDAu;
  unsigned x0 = c0 + k0, x1 = c1 + k1;
#define TF_R4(a,b,c,d) { x0 += x1; x1 = rotl32(x1,a); x1 ^= x0; \
                         x0 += x1; x1 = rotl32(x1,b); x1 ^= x0; \
                         x0 += x1; x1 = rotl32(x1,c); x1 ^= x0; \
                         x0 += x1; x1 = rotl32(x1,d); x1 ^= x0; }
  TF_R4(13,15,26,6);  x0 += k1;  x1 += ks2 + 1u;
  TF_R4(17,29,16,24); x0 += ks2; x1 += k0  + 2u;
  TF_R4(13,15,26,6);  x0 += k0;  x1 += k1  + 3u;
  TF_R4(17,29,16,24); x0 += k1;  x1 += ks2 + 4u;
  TF_R4(13,15,26,6);  x0 += ks2; x1 += k0  + 5u;
#undef TF_R4
  o0 = x0; o1 = x1;
}

// split(key) -> (new_key, subkey), matching jax.random.split(key, 2)
__device__ __forceinline__ void jax_split2(unsigned k0, unsigned k1,
                                           unsigned &nk0, unsigned &nk1,
                                           unsigned &sk0, unsigned &sk1) {
#if JAX_PARTITIONABLE
  tf2x32(k0, k1, 0u, 0u, nk0, nk1);
  tf2x32(k0, k1, 0u, 1u, sk0, sk1);
#else
  unsigned a0, a1, b0, b1;
  tf2x32(k0, k1, 0u, 2u, a0, a1);
  tf2x32(k0, k1, 1u, 3u, b0, b1);
  nk0 = a0; nk1 = b0; sk0 = a1; sk1 = b1;
#endif
}

// ---------------------------------------------------------------------------
// Fused RNG + x2 kernel.
//  blocks [0, R_):        permutation init via 2 rounds of bitonic stable sort
//                         (1024 threads: 2 compare-exchanges per pass instead
//                         of 8 -> ~4x less serial latency per barrier pass)
//  blocks [R_, R_+2048):  x2[row] = ||pts[row]||^2, 16 rows per block.
//                         Runs on the 248 CUs the rng blocks don't use.
// ---------------------------------------------------------------------------
__global__ __launch_bounds__(1024) void k_rng_x2(const float* __restrict__ pts,
                                                 float* __restrict__ x2,
                                                 int* __restrict__ init_idx) {
  __shared__ unsigned long long arr[N_];
  __shared__ unsigned short perm[N_];
  const int t = threadIdx.x;

  if (blockIdx.x >= R_) {
    // ---- x2 part: 16 rows per block, one wave per row ----
    const int row = (blockIdx.x - R_) * 16 + (t >> 6);
    const int lane = t & 63;
    const float4* P = (const float4*)(pts + (size_t)row * D_);
    float s = 0.f;
#pragma unroll
    for (int i = 0; i < 4; ++i) {
      float4 v = P[lane + 64 * i];
      s += v.x * v.x + v.y * v.y + v.z * v.z + v.w * v.w;
    }
#pragma unroll
    for (int m = 32; m > 0; m >>= 1) s += __shfl_down(s, m);
    if (lane == 0) x2[row] = s;
    return;
  }

  // ---- rng part ----
  const int r = blockIdx.x;

  // key_r = split(key(42), 8)[r]
  unsigned k0, k1;
#if JAX_PARTITIONABLE
  tf2x32(0u, 42u, 0u, (unsigned)r, k0, k1);
#else
  {
    unsigned a0, a1, b0, b1;
    unsigned i0 = 2u * r, i1 = 2u * r + 1u;
    if (r < 4) { tf2x32(0u, 42u, i0, i0 + 8u, a0, a1); tf2x32(0u, 42u, i1, i1 + 8u, b0, b1); k0 = a0; k1 = b0; }
    else       { tf2x32(0u, 42u, i0 - 8u, i0, a0, a1); tf2x32(0u, 42u, i1 - 8u, i1, b0, b1); k0 = a1; k1 = b1; }
  }
#endif

  for (int i = t; i < N_; i += 1024) perm[i] = (unsigned short)i;
  __syncthreads();

  for (int round = 0; round < 2; ++round) {
    unsigned nk0, nk1, sk0, sk1;
    jax_split2(k0, k1, nk0, nk1, sk0, sk1);
    // sort keys for all 4096 positions
    for (int j = t; j < N_; j += 1024) {
      unsigned o0, o1, skey;
#if JAX_PARTITIONABLE
      tf2x32(sk0, sk1, 0u, (unsigned)j, o0, o1);
      skey = o0 ^ o1;
#else
      if (j < 2048) { tf2x32(sk0, sk1, (unsigned)j, (unsigned)(j + 2048), o0, o1); skey = o0; }
      else          { tf2x32(sk0, sk1, (unsigned)(j - 2048), (unsigned)j, o0, o1); skey = o1; }
#endif
      arr[j] = ((unsigned long long)skey << 24) |
               ((unsigned long long)(unsigned)j << 12) |
               (unsigned long long)perm[j];
    }
    __syncthreads();
    // bitonic sort ascending, 4096 elements (stable via slot bits)
    for (int k = 2; k <= N_; k <<= 1) {
      for (int j2 = k >> 1; j2 >= 1; j2 >>= 1) {
        for (int q = t; q < N_ / 2; q += 1024) {
          int low = q & (j2 - 1);
          int i0 = ((q ^ low) << 1) | low;
          int i1 = i0 | j2;
          bool up = ((i0 & k) == 0);
          unsigned long long a = arr[i0], b = arr[i1];
          if ((a > b) == up) { arr[i0] = b; arr[i1] = a; }
        }
        __syncthreads();
      }
    }
    for (int j = t; j < N_; j += 1024) perm[j] = (unsigned short)(arr[j] & 0xFFFull);
    __syncthreads();
    k0 = nk0; k1 = nk1;
  }
  if (t < L_) init_idx[r * L_ + t] = (int)perm[t];
}

// ---------------------------------------------------------------------------
// Gather initial centers + c2; also zero-init counts for iteration 0.
// One block per (r,l).
// ---------------------------------------------------------------------------
__global__ __launch_bounds__(256) void k_gather_init(const float* __restrict__ pts,
                                                     const int* __restrict__ init_idx,
                                                     float* __restrict__ centers,
                                                     float* __restrict__ c2,
                                                     int* __restrict__ counts) {
  const int l = blockIdx.x, r = blockIdx.y, t = threadIdx.x;
  const int idx = init_idx[r * L_ + l];
  const float4* src = (const float4*)(pts + ((size_t)r * N_ + idx) * D_);
  float4* dst = (float4*)(centers + ((size_t)r * L_ + l) * D_);
  float4 v = src[t];
  dst[t] = v;
  float s = v.x * v.x + v.y * v.y + v.z * v.z + v.w * v.w;
  __shared__ float red[4];
  const int lane = t & 63, wave = t >> 6;
#pragma unroll
  for (int m = 32; m > 0; m >>= 1) s += __shfl_down(s, m);
  if (lane == 0) red[wave] = s;
  __syncthreads();
  if (t == 0) {
    c2[r * L_ + l] = red[0] + red[1] + red[2] + red[3];
    counts[r * L_ + l] = 0;
  }
}

// ---------------------------------------------------------------------------
// Assignment: labels[r][n] = argmin_l (x2[n] + c2[l]) - 2*dot(pts[n],centers[l])
// Block = 256 threads, tile = 128 points x 64 clusters, k-chunks of 64.
// DOUBLE-BUFFERED: next K-tile is loaded into registers before the compute
// phase (its ~4096-cycle FMA block hides the global latency), written to the
// other LDS buffer after compute; ONE barrier per K-step instead of two.
// Also accumulates per-cluster counts (LDS hist + integer atomics ->
// bit-deterministic), replacing the separate k_counts kernel.
// ---------------------------------------------------------------------------
#define BN 128
#define BK 64
__global__ __launch_bounds__(256, 1) void k_assign(const float* __restrict__ pts,
                                                   const float* __restrict__ centers,
                                                   const float* __restrict__ c2g,
                                                   const float* __restrict__ x2g,
                                                   int* __restrict__ labels,
                                                   int* __restrict__ counts) {
  __shared__ __align__(16) float pT[2][BK][BN + 4];   // [buf][kk][p], stride 132
  __shared__ __align__(16) float cT[2][BK][L_ + 4];   // [buf][kk][l], stride 68
  __shared__ int hist[L_];
  const int t = threadIdx.x;
  const int r = blockIdx.y;
  const int n0 = blockIdx.x * BN;
  const int pg = t >> 3;        // 0..31
  const int cg = t & 7;         // 0..7
  const int p0 = pg * 4;
  const int l0 = cg * 8;

  const float* Pr = pts + ((size_t)r * N_ + n0) * D_;
  const float* Cr = centers + (size_t)r * L_ * D_;

  // per-thread staging coordinates: idx = i*256+t -> row = i*16 + (t>>4),
  // kk = (t&15)*4   (identical mapping to the verified single-buffer version)
  const int srow = t >> 4;       // 0..15
  const int skk  = (t & 15) * 4; // 0..60

  if (t < L_) hist[t] = 0;

  float4 pv[8], cv[4];

  // prologue: load K-tile 0 into regs, write buffer 0
#pragma unroll
  for (int i = 0; i < 8; ++i)
    pv[i] = *(const float4*)(Pr + (size_t)(i * 16 + srow) * D_ + skk);
#pragma unroll
  for (int i = 0; i < 4; ++i)
    cv[i] = *(const float4*)(Cr + (size_t)(i * 16 + srow) * D_ + skk);
#pragma unroll
  for (int i = 0; i < 8; ++i) {
    const int p = i * 16 + srow;
    pT[0][skk + 0][p] = pv[i].x; pT[0][skk + 1][p] = pv[i].y;
    pT[0][skk + 2][p] = pv[i].z; pT[0][skk + 3][p] = pv[i].w;
  }
#pragma unroll
  for (int i = 0; i < 4; ++i) {
    const int l = i * 16 + srow;
    cT[0][skk + 0][l] = cv[i].x; cT[0][skk + 1][l] = cv[i].y;
    cT[0][skk + 2][l] = cv[i].z; cT[0][skk + 3][l] = cv[i].w;
  }
  __syncthreads();

  float acc[4][8];
#pragma unroll
  for (int i = 0; i < 4; ++i)
#pragma unroll
    for (int j = 0; j < 8; ++j) acc[i][j] = 0.f;

  constexpr int NKB = D_ / BK;   // 16
  for (int kb = 0; kb < NKB; ++kb) {
    const int cur = kb & 1;
    // issue next tile's global loads early: latency hides under compute
    if (kb + 1 < NKB) {
      const int kbase = (kb + 1) * BK;
#pragma unroll
      for (int i = 0; i < 8; ++i)
        pv[i] = *(const float4*)(Pr + (size_t)(i * 16 + srow) * D_ + kbase + skk);
#pragma unroll
      for (int i = 0; i < 4; ++i)
        cv[i] = *(const float4*)(Cr + (size_t)(i * 16 + srow) * D_ + kbase + skk);
    }

    for (int kk = 0; kk < BK; ++kk) {
      float4 pvv = *(const float4*)&pT[cur][kk][p0];
      float4 ca  = *(const float4*)&cT[cur][kk][l0];
      float4 cb  = *(const float4*)&cT[cur][kk][l0 + 4];
      float pvs[4] = {pvv.x, pvv.y, pvv.z, pvv.w};
      float cvs[8] = {ca.x, ca.y, ca.z, ca.w, cb.x, cb.y, cb.z, cb.w};
#pragma unroll
      for (int i = 0; i < 4; ++i)
#pragma unroll
        for (int j = 0; j < 8; ++j)
          acc[i][j] = fmaf(pvs[i], cvs[j], acc[i][j]);
    }

    // write the prefetched tile into the other buffer (last read at kb-1,
    // protected by the barrier at the end of kb-1)
    if (kb + 1 < NKB) {
      const int nxt = cur ^ 1;
#pragma unroll
      for (int i = 0; i < 8; ++i) {
        const int p = i * 16 + srow;
        pT[nxt][skk + 0][p] = pv[i].x; pT[nxt][skk + 1][p] = pv[i].y;
        pT[nxt][skk + 2][p] = pv[i].z; pT[nxt][skk + 3][p] = pv[i].w;
      }
#pragma unroll
      for (int i = 0; i < 4; ++i) {
        const int l = i * 16 + srow;
        cT[nxt][skk + 0][l] = cv[i].x; cT[nxt][skk + 1][l] = cv[i].y;
        cT[nxt][skk + 2][l] = cv[i].z; cT[nxt][skk + 3][l] = cv[i].w;
      }
    }
    __syncthreads();
  }

  // epilogue: d2 and argmin (first-min tie-break, matching jnp.argmin)
  float c2v[8];
#pragma unroll
  for (int j = 0; j < 8; ++j) c2v[j] = c2g[r * L_ + l0 + j];

#pragma unroll
  for (int i = 0; i < 4; ++i) {
    const int n = n0 + p0 + i;
    const float x2i = x2g[r * N_ + n];
    float bv = 3.4e38f;
    int bi = 0;
#pragma unroll
    for (int j = 0; j < 8; ++j) {
      float d2 = (x2i + c2v[j]) - 2.0f * acc[i][j];
      if (d2 < bv) { bv = d2; bi = l0 + j; }
    }
    // reduce across the 8 cluster-groups (consecutive lanes pg*8..pg*8+7)
#pragma unroll
    for (int m = 1; m < 8; m <<= 1) {
      float ov = __shfl_xor(bv, m);
      int oi = __shfl_xor(bi, m);
      if (ov < bv || (ov == bv && oi < bi)) { bv = ov; bi = oi; }
    }
    if (cg == 0) {
      labels[r * N_ + n] = bi;
      atomicAdd(&hist[bi], 1);          // block-local histogram (deterministic)
    }
  }
  __syncthreads();
  if (t < L_) atomicAdd(&counts[r * L_ + t], hist[t]);  // integer: bit-exact
}

// ---------------------------------------------------------------------------
// Partial per-cluster sums. Block = (dchunk, seg, r): accumulates 512 points
// over 256 dims into a 64KB LDS accumulator, then writes its partial slab.
// Fully deterministic (fixed order), no global atomics.
// ---------------------------------------------------------------------------
__global__ __launch_bounds__(256) void k_update(const float* __restrict__ pts,
                                                const int* __restrict__ labels,
                                                float* __restrict__ psums) {
  __shared__ float acc[L_ * 256];
  __shared__ int lab[512];
  const int dch = blockIdx.x;   // 0..3
  const int seg = blockIdx.y;   // 0..7
  const int r   = blockIdx.z;   // 0..7
  const int t = threadIdx.x;

  for (int i = t; i < L_ * 256; i += 256) acc[i] = 0.f;
  for (int i = t; i < 512; i += 256) lab[i] = labels[r * N_ + seg * 512 + i];
  __syncthreads();

  const float* P = pts + ((size_t)r * N_ + seg * 512) * D_ + dch * 256 + t;
#pragma unroll 4
  for (int n = 0; n < 512; ++n) {
    int l = lab[n];
    acc[l * 256 + t] += P[(size_t)n * D_];
  }
  __syncthreads();

  float* S = psums + (((size_t)r * SEGS + seg) * L_) * D_ + dch * 256;
  for (int i = t; i < L_ * 256; i += 256) {
    int l = i >> 8, dd = i & 255;
    S[(size_t)l * D_ + dd] = acc[i];
  }
}

// ---------------------------------------------------------------------------
// Reduce partial sums -> new centers (+ c2). One block per (r,l).
// new_c = counts>0 ? sums / max(counts,1) : old_c   (IEEE fp32 division)
// Re-zeroes counts for the next iteration's k_assign histogram.
// ---------------------------------------------------------------------------
__global__ __launch_bounds__(256) void k_reduce(const float* __restrict__ psums,
                                                int* __restrict__ counts,
                                                float* __restrict__ centers,
                                                float* __restrict__ c2) {
  const int l = blockIdx.x, r = blockIdx.y, t = threadIdx.x;
  const int cnt = counts[r * L_ + l];
  const float denom = fmaxf((float)cnt, 1.0f);

  float4 s = {0.f, 0.f, 0.f, 0.f};
#pragma unroll
  for (int seg = 0; seg < SEGS; ++seg) {
    const float4 v = *(const float4*)(psums + (((size_t)r * SEGS + seg) * L_ + l) * D_ + t * 4);
    s.x += v.x; s.y += v.y; s.z += v.z; s.w += v.w;
  }
  float4* Crow = (float4*)(centers + ((size_t)r * L_ + l) * D_);
  float4 cn;
  if (cnt > 0) {
    cn.x = s.x / denom; cn.y = s.y / denom; cn.z = s.z / denom; cn.w = s.w / denom;
  } else {
    cn = Crow[t];
  }
  Crow[t] = cn;

  float ssq = cn.x * cn.x + cn.y * cn.y + cn.z * cn.z + cn.w * cn.w;
  __shared__ float red[4];
  const int lane = t & 63, wave = t >> 6;
#pragma unroll
  for (int m = 32; m > 0; m >>= 1) ssq += __shfl_down(ssq, m);
  if (lane == 0) red[wave] = ssq;
  __syncthreads();
  if (t == 0) {
    c2[r * L_ + l] = red[0] + red[1] + red[2] + red[3];
    counts[r * L_ + l] = 0;   // all threads read cnt before this barrier
  }
}

// ---------------------------------------------------------------------------
// Final gather: out[row] = centers[r][labels[row]] — 4 rows per block.
// ---------------------------------------------------------------------------
__global__ __launch_bounds__(256) void k_final(const float* __restrict__ centers,
                                               const int* __restrict__ labels,
                                               float* __restrict__ out) {
  const int t = threadIdx.x;
  const int row = blockIdx.x * 4 + (t >> 6);
  const int lane = t & 63;
  const int r = row >> 12;
  const int lab = labels[row];
  const float4* src = (const float4*)(centers + ((size_t)r * L_ + lab) * D_);
  float4* dst = (float4*)(out + (size_t)row * D_);
#pragma unroll
  for (int i = 0; i < 4; ++i) dst[lane + 64 * i] = src[lane + 64 * i];
}

// ---------------------------------------------------------------------------
extern "C" void kernel_launch(void* const* d_in, const int* in_sizes, int n_in,
                              void* d_out, int out_size, void* d_ws, size_t ws_size,
                              hipStream_t stream) {
  const float* x = (const float*)d_in[0];   // [512, 65536] == pts [8][4096][1024]
  float* out = (float*)d_out;               // [512, 65536] float32
  char* ws = (char*)d_ws;

  // workspace layout (bytes)
  float* centers = (float*)(ws + 0);                        // 2 MB
  float* c2      = (float*)(ws + 2097152);                  // 2 KB
  float* x2      = (float*)(ws + 2099200);                  // 128 KB
  int*   labels  = (int*)  (ws + 2230272);                  // 128 KB
  int*   counts  = (int*)  (ws + 2361344);                  // 2 KB
  int*   initidx = (int*)  (ws + 2363392);                  // 2 KB
  float* psums   = (float*)(ws + 2365440);                  // 16 MB
  (void)in_sizes; (void)n_in; (void)out_size; (void)ws_size;

  // fused rng (8 blocks) + x2 (2048 blocks) — x2 hides under the bitonic sort
  k_rng_x2<<<dim3(R_ + ROWS / 16), 1024, 0, stream>>>(x, x2, initidx);
  k_gather_init<<<dim3(L_, R_), 256, 0, stream>>>(x, initidx, centers, c2, counts);

  for (int it = 0; it < ITERS; ++it) {
    k_assign<<<dim3(N_ / BN, R_), 256, 0, stream>>>(x, centers, c2, x2, labels, counts);
    k_update<<<dim3(4, SEGS, R_), 256, 0, stream>>>(x, labels, psums);
    k_reduce<<<dim3(L_, R_), 256, 0, stream>>>(psums, counts, centers, c2);
  }
  k_assign<<<dim3(N_ / BN, R_), 256, 0, stream>>>(x, centers, c2, x2, labels, counts);
  k_final<<<dim3(ROWS / 4), 256, 0, stream>>>(centers, labels, out);
}